// Round 4
// baseline (171.624 us; speedup 1.0000x reference)
//
#include <hip/hip_runtime.h>
#include <hip/hip_bf16.h>

// GCN layer: out = (D^-1/2 A D^-1/2 X) W^T + b
// Round 14: sharded-slot DIRECT ELL build. R13 proved contention DEPTH is
// the atomic floor mechanism (24-deep reservation ~free vs 391-deep ~50us;
// R12 direct build 16-deep = 57us). So shard the ELL slots 4-way by block
// group: atomicAdd(&degsh[row*4 + (blk&3)]) -> ~4-deep contention on 200K
// addresses. Eliminates: pairs array, both LDS-hist phases (k_bin), the
// pairs re-scan + LDS ELL build + barrier in k_fused (R13's +4us regression,
// 413K bank conflicts), and k_deg's re-scan (degree = sum of 4 counters).
//   k_build: W cast + xs=bf16(x) cast (overlap) + direct sharded ELL build.
//   k_dis:   dis[r] = rsqrt(sum degsh[r*4..]) tiny map (200KB, L2-hot).
//   k_fused: R10/R12-lean gather (no build phase): uniform s_load_dwordx4
//     of counters, lane->(shard,slot) select chain, coalesced ell row read,
//     per-lane dis[c] gather + readlane broadcast, verified MFMA epilogue.
//
// ws: degsh[N*4 i32] 800KB | ell[N*96 u16] 9.6MB | dis[nrows f32] 200KB |
//     xs[nrows*128 bf16] 12.85MB | wb 32KB  ~= 23.5 MB

typedef short v8s __attribute__((ext_vector_type(8)));
typedef float v4f __attribute__((ext_vector_type(4)));

#define NSH 4         // ELL slot shards per row
#define SHCAP 24      // per-(row,shard) ~Poisson(4); P(>24)~1e-12/cell. Guarded.
#define ELLSTRIDE 96  // NSH*SHCAP shorts = 192 B/row (64B-aligned rows)
#define ROWSTRIDE 136 // 128 bf16 + 8 pad shorts; 272 B rows (16B-aligned)

static __device__ __forceinline__ unsigned int f2bf(float f) {
    __hip_bfloat16 h = __float2bfloat16(f);  // RNE
    return (unsigned int)__builtin_bit_cast(unsigned short, h);
}

// k_build: blocks [0,16): W cast. [16,16+ncast): xs cast (4096 dwords each).
// Rest: 2048 edges each; slot = atomicAdd(degsh[row*4+shard]) (~4-deep),
// scatter col into ell[row*96 + shard*24 + slot].
__global__ __launch_bounds__(256) void k_build(
    const int* __restrict__ idx, int* __restrict__ degsh,
    unsigned short* __restrict__ ell, const float4* __restrict__ w4,
    ushort4* __restrict__ wb4, const float2* __restrict__ x2,
    unsigned int* __restrict__ xs32, int E, int ncast, int N) {
    int b = blockIdx.x;
    const int t = threadIdx.x;
    if (b < 16) {  // W cast: 16 blocks x 256 thr = 4096 float4s
        int i = b * 256 + t;
        float4 v = w4[i];
        ushort4 o;
        o.x = (unsigned short)f2bf(v.x);
        o.y = (unsigned short)f2bf(v.y);
        o.z = (unsigned short)f2bf(v.z);
        o.w = (unsigned short)f2bf(v.w);
        wb4[i] = o;
        return;
    }
    b -= 16;
    if (b < ncast) {  // xs cast: 4096 dwords (64 rows) per block, unscaled
        int base = b * 4096;
#pragma unroll 4
        for (int it = 0; it < 16; ++it) {
            int i = base + it * 256 + t;
            int lr = i >> 6;  // global row
            unsigned ov = 0u;
            if (lr < N) {
                float2 v = x2[i];
                ov = f2bf(v.x) | (f2bf(v.y) << 16);
            }
            xs32[i] = ov;  // rows >= N (incl. pad row N) -> zeros
        }
        return;
    }
    b -= ncast;
    const int shard = b & (NSH - 1);
    int e0 = b * 2048 + t * 8;
    int nv = E - e0;
    nv = nv > 8 ? 8 : (nv < 0 ? 0 : nv);
    int rows[8], cols[8];
    if (nv == 8) {
        int4 a0 = *(const int4*)&idx[e0];
        int4 a1 = *(const int4*)&idx[e0 + 4];
        int4 c0 = *(const int4*)&idx[E + e0];
        int4 c1 = *(const int4*)&idx[E + e0 + 4];
        rows[0] = a0.x; rows[1] = a0.y; rows[2] = a0.z; rows[3] = a0.w;
        rows[4] = a1.x; rows[5] = a1.y; rows[6] = a1.z; rows[7] = a1.w;
        cols[0] = c0.x; cols[1] = c0.y; cols[2] = c0.z; cols[3] = c0.w;
        cols[4] = c1.x; cols[5] = c1.y; cols[6] = c1.z; cols[7] = c1.w;
    } else {
        for (int k = 0; k < 8; ++k) {
            rows[k] = (k < nv) ? idx[e0 + k] : 0;
            cols[k] = (k < nv) ? idx[E + e0 + k] : 0;
        }
    }
#pragma unroll
    for (int k = 0; k < 8; ++k) {
        if (k < nv) {
            int slot = atomicAdd(&degsh[rows[k] * NSH + shard], 1);  // ~4-deep
            if (slot < SHCAP)
                ell[(size_t)rows[k] * ELLSTRIDE + shard * SHCAP + slot] =
                    (unsigned short)cols[k];
        }
    }
}

// k_dis: dis[r] = rsqrt(true degree) (0 for deg==0 and rows >= N, incl. pad).
__global__ __launch_bounds__(256) void k_dis(const int4* __restrict__ degsh4,
                                             float* __restrict__ dis, int N,
                                             int nrows) {
    int r = blockIdx.x * 256 + threadIdx.x;
    if (r >= nrows) return;
    float v = 0.f;
    if (r < N) {
        int4 c = degsh4[r];
        int d = c.x + c.y + c.z + c.w;  // true degree (uncapped)
        if (d > 0) v = rsqrtf((float)d);
    }
    dis[r] = v;
}

// k_fused: 256 thr (4 waves), 32 rows/block. No build phase. Per row:
// uniform s_load_dwordx4 counters -> lane->(shard,slot) select chain ->
// coalesced ell row read -> per-lane dis[c] -> 16-batch readlane gather ->
// verified MFMA epilogue.
__global__ __launch_bounds__(256) void k_fused(
    const unsigned short* __restrict__ ell, const int* __restrict__ degsh,
    const float* __restrict__ dis, const unsigned int* __restrict__ xs32,
    const v8s* __restrict__ Wb8, const float* __restrict__ bias,
    float* __restrict__ out, int N) {
    __shared__ __align__(16) unsigned short smem[32 * ROWSTRIDE];
    const int nb0 = blockIdx.x * 32;
    const int wv = threadIdx.x >> 6, lane = threadIdx.x & 63;

    for (int i = 0; i < 8; ++i) {
        int lrow = wv * 8 + i;
        int n = nb0 + lrow;
        float acc0 = 0.f, acc1 = 0.f;
        if (n < N) {
            const int4 c4 = *(const int4*)&degsh[n * NSH];  // uniform s_load
            int c0 = c4.x > SHCAP ? SHCAP : c4.x;
            int c1 = c4.y > SHCAP ? SHCAP : c4.y;
            int c2 = c4.z > SHCAP ? SHCAP : c4.z;
            int c3 = c4.w > SHCAP ? SHCAP : c4.w;
            int a1 = c0, a2 = a1 + c1, a3 = a2 + c2;
            int d = a3 + c3;
            d = d > 64 ? 64 : d;  // lane coverage; P(deg>64) ~ 1e-19
            // lane -> (shard, slot)
            int sh = (lane >= a1) + (lane >= a2) + (lane >= a3);
            int base = sh == 0 ? 0 : (sh == 1 ? a1 : (sh == 2 ? a2 : a3));
            int ei = (lane < d) ? (sh * SHCAP + lane - base) : 0;  // in-row
            int cl = ell[(size_t)n * ELLSTRIDE + ei];  // coalesced 192B row
            int c = (lane < d) ? cl : N;               // pad -> zero row
            float dcf = dis[c];  // per-lane, 200KB L2-hot
            int dcb = __builtin_bit_cast(int, dcf);
            for (int j = 0; j < d; j += 16) {  // j in {0,16,32,48}
                int cc[16];
#pragma unroll
                for (int u = 0; u < 16; ++u)
                    cc[u] = __builtin_amdgcn_readlane(c, j + u);
                unsigned uu[16];
#pragma unroll
                for (int u = 0; u < 16; ++u)
                    uu[u] = xs32[(size_t)cc[u] * 64 + lane];
                float sc[16];
#pragma unroll
                for (int u = 0; u < 16; ++u)
                    sc[u] = __builtin_bit_cast(
                        float, __builtin_amdgcn_readlane(dcb, j + u));
#pragma unroll
                for (int u = 0; u < 16; ++u) {
                    acc0 = fmaf(sc[u], __builtin_bit_cast(float, uu[u] << 16), acc0);
                    acc1 = fmaf(sc[u],
                                __builtin_bit_cast(float, uu[u] & 0xFFFF0000u), acc1);
                }
            }
            float s = dis[n];  // = rsqrt(true deg), uniform s_load
            acc0 *= s;
            acc1 *= s;
        }
        unsigned pack = f2bf(acc0) | (f2bf(acc1) << 16);
        *(unsigned int*)&smem[(size_t)lrow * ROWSTRIDE + lane * 2] = pack;
    }
    __syncthreads();

    // MFMA (verified layout: A m=lane&15 k=quad*8+i; B row-major W bf16;
    // C/D col=lane&15 row=quad*4+reg). Wave: rows (wv&1)*16, cols (wv>>1)*64.
    {
        int quad = lane >> 4, m16 = lane & 15;
        int lrow = (wv & 1) * 16 + m16;
        v8s afrag[4];
#pragma unroll
        for (int kk = 0; kk < 4; ++kk)
            afrag[kk] = *(const v8s*)&smem[lrow * ROWSTRIDE + kk * 32 + quad * 8];
        int rbase = nb0 + (wv & 1) * 16 + quad * 4;
        int jbase = (wv >> 1) * 64;
#pragma unroll
        for (int jt = 0; jt < 4; ++jt) {
            int jcol = jbase + jt * 16 + m16;
            v4f acc = {0.f, 0.f, 0.f, 0.f};
#pragma unroll
            for (int kk = 0; kk < 4; ++kk) {
                v8s bfrag = Wb8[jcol * 16 + kk * 4 + quad];
                acc = __builtin_amdgcn_mfma_f32_16x16x32_bf16(afrag[kk], bfrag,
                                                              acc, 0, 0, 0);
            }
            float bj = bias[jcol];
#pragma unroll
            for (int r = 0; r < 4; ++r) {
                int row = rbase + r;
                if (row < N) out[(size_t)row * 128 + jcol] = acc[r] + bj;
            }
        }
    }
}

extern "C" void kernel_launch(void* const* d_in, const int* in_sizes, int n_in,
                              void* d_out, int out_size, void* d_ws, size_t ws_size,
                              hipStream_t stream) {
    const float* x = (const float*)d_in[0];
    const int* idx = (const int*)d_in[1];
    const float* W = (const float*)d_in[2];
    const float* b = (const float*)d_in[3];
    float* out = (float*)d_out;

    const int N = in_sizes[0] / 128;    // 50000
    const int E = in_sizes[1] / 2;      // 800000
    const int nbins = (N + 255) / 256;  // 196
    const int nrows = nbins * 256;      // 50176 (covers pad row N)
    const int ncast = nbins * 4;        // 784 blocks x 4096 dwords = nrows*64

    char* p = (char*)d_ws;
    auto alloc = [&](size_t bytes) {
        char* r = p;
        p += (bytes + 63) & ~(size_t)63;
        return r;
    };
    int* degsh = (int*)alloc((size_t)N * NSH * 4);                         // 800 KB
    unsigned short* ell = (unsigned short*)alloc((size_t)N * ELLSTRIDE * 2);  // 9.6 MB
    float* dis = (float*)alloc((size_t)nrows * 4);                         // 200 KB
    unsigned int* xs = (unsigned int*)alloc((size_t)nrows * 128 * 2);      // 12.85 MB
    ushort4* wb = (ushort4*)alloc(128 * 128 * 2);                          // 32 KB

    hipMemsetAsync(degsh, 0, (size_t)N * NSH * sizeof(int), stream);

    // 16 W-cast + 784 xs-cast + 391 ELL-build blocks, all concurrent
    const int bblocks = 16 + ncast + (E + 2047) / 2048;
    k_build<<<bblocks, 256, 0, stream>>>(idx, degsh, ell, (const float4*)W, wb,
                                         (const float2*)x, xs, E, ncast, N);
    k_dis<<<nrows / 256, 256, 0, stream>>>((const int4*)degsh, dis, N, nrows);
    k_fused<<<(N + 31) / 32, 256, 0, stream>>>(ell, degsh, dis, xs,
                                               (const v8s*)wb, b, out, N);
}